// Round 12
// baseline (60296.838 us; speedup 1.0000x reference)
//
#include <hip/hip_runtime.h>
#include <math.h>

#define TMAX 200
#define NCL  16
#define CB   32

__device__ __forceinline__ float sig_(float x){ return 1.0f/(1.0f+expf(-x)); }

// Light cluster barrier: one atomicAdd + go flag, single poller per block.
__device__ __forceinline__ void cl_sync(int* cnt, int* go, int nblk, int ep, int tid)
{
    __syncthreads();
    if (tid == 0) {
        __threadfence();
        int old = __hip_atomic_fetch_add(cnt, 1, __ATOMIC_ACQ_REL, __HIP_MEMORY_SCOPE_AGENT);
        if (old == nblk - 1) {
            __hip_atomic_store(cnt, 0, __ATOMIC_RELAXED, __HIP_MEMORY_SCOPE_AGENT);
            __hip_atomic_store(go, ep, __ATOMIC_RELEASE, __HIP_MEMORY_SCOPE_AGENT);
        } else {
            while (__hip_atomic_load(go, __ATOMIC_ACQUIRE, __HIP_MEMORY_SCOPE_AGENT) < ep)
                __builtin_amdgcn_s_sleep(16);
        }
        __threadfence();
    }
    __syncthreads();
}

// LDS floats: XS[2][32][36] @0 (2304); WS @2304 (A 2x3200, B 2x1152, C 2x384)
// A epi: gi[96][33] @0 ; hb[32][33] @4096.  B epi: hab[32][33] @0.
// C: red[2][8][8][33] @3072 ; pb[32][24] @7296.
#define LDSF 8704

__global__ __launch_bounds__(256, 2)
void kfused(const int* __restrict__ lengths,
            const float* __restrict__ eps,
            const float* __restrict__ W_ih, const float* __restrict__ b_ih,
            const float* __restrict__ b_hh,
            const float* __restrict__ W1a, const float* __restrict__ b1a,
            const float* __restrict__ W1b, const float* __restrict__ b1b,
            const float* __restrict__ W2a, const float* __restrict__ b2a,
            const float* __restrict__ W2b, const float* __restrict__ b2b,
            float* __restrict__ out_p1, float* __restrict__ out_p2, float* __restrict__ out_h,
            int* __restrict__ bar, float* __restrict__ xT, float* __restrict__ hT,
            float* __restrict__ haT, int nblk)
{
    __shared__ float lds[LDSF];
    __shared__ int sbs[TMAX], soff[TMAX];

    const int tid = threadIdx.x;
    const int bid = blockIdx.x;
    const int cl  = bid & 15;            // cluster
    const int r   = bid >> 4;            // rank in cluster
    const int cb  = cl * CB;

    int* cnt = &bar[cl * 16];
    int* go  = &bar[cl * 16 + 8];

    if (tid < TMAX) {
        int c = 0;
        for (int b = 0; b < 512; ++b) c += (lengths[b] > tid) ? 1 : 0;
        sbs[tid] = c;
    }
    __syncthreads();
    if (tid == 0) { int a = 0; for (int i = 0; i < TMAX; ++i) { soff[i] = a; a += sbs[i]; } }
    __syncthreads();

    for (int t = 0; t < TMAX; ++t) {
        const int bsz = sbs[t], ofs = soff[t];

        // ================= phase A: gi = x @ W_ih^T -> GRU -> h =================
        for (int s = r; s < 32; s += nblk) {
            const int j0 = s * 32;
            const int tx = tid & 15, ty = tid >> 4;
            float acc[2][6];
            #pragma unroll
            for (int i = 0; i < 2; ++i)
                #pragma unroll
                for (int q = 0; q < 6; ++q) acc[i][q] = 0.f;

            if (t > 0) {
                const int sk = tid >> 3, sb = (tid & 7) * 4;
                const int wj = tid >> 3, wk = (tid & 7) * 4;
                float4 px, pw0, pw1, pw2;
                px  = *(const float4*)&xT[(size_t)sk * 512 + cb + sb];
                pw0 = *(const float4*)&W_ih[(size_t)(j0 + wj) * 256 + wk];
                pw1 = *(const float4*)&W_ih[(size_t)(1024 + j0 + wj) * 256 + wk];
                pw2 = *(const float4*)&W_ih[(size_t)(2048 + j0 + wj) * 256 + wk];
                {
                    float* xs = lds; float* ws = lds + 2304;
                    *(float4*)&xs[sk * 36 + sb] = px;
                    const float* a0 = &pw0.x; const float* a1 = &pw1.x; const float* a2 = &pw2.x;
                    #pragma unroll
                    for (int m = 0; m < 4; ++m) {
                        ws[(wk+m)*100 + wj]      = a0[m];
                        ws[(wk+m)*100 + 32 + wj] = a1[m];
                        ws[(wk+m)*100 + 64 + wj] = a2[m];
                    }
                }
                for (int kc = 0; kc < 8; ++kc) {
                    __syncthreads();
                    const int cur = kc & 1;
                    if (kc < 7) {
                        const int kb = (kc + 1) * 32;
                        px  = *(const float4*)&xT[(size_t)(kb + sk) * 512 + cb + sb];
                        pw0 = *(const float4*)&W_ih[(size_t)(j0 + wj) * 256 + kb + wk];
                        pw1 = *(const float4*)&W_ih[(size_t)(1024 + j0 + wj) * 256 + kb + wk];
                        pw2 = *(const float4*)&W_ih[(size_t)(2048 + j0 + wj) * 256 + kb + wk];
                    }
                    const float* xs = lds + cur * 1152;
                    const float* ws = lds + 2304 + cur * 3200;
                    #pragma unroll 4
                    for (int kk = 0; kk < 32; ++kk) {
                        const float a0v = xs[kk*36 + ty*2];
                        const float a1v = xs[kk*36 + ty*2 + 1];
                        #pragma unroll
                        for (int q = 0; q < 6; ++q) {
                            const float w = ws[kk*100 + tx*6 + q];
                            acc[0][q] = fmaf(a0v, w, acc[0][q]);
                            acc[1][q] = fmaf(a1v, w, acc[1][q]);
                        }
                    }
                    if (kc < 7) {
                        float* xs2 = lds + (cur ^ 1) * 1152;
                        float* ws2 = lds + 2304 + (cur ^ 1) * 3200;
                        *(float4*)&xs2[sk * 36 + sb] = px;
                        const float* a0 = &pw0.x; const float* a1 = &pw1.x; const float* a2 = &pw2.x;
                        #pragma unroll
                        for (int m = 0; m < 4; ++m) {
                            ws2[(wk+m)*100 + wj]      = a0[m];
                            ws2[(wk+m)*100 + 32 + wj] = a1[m];
                            ws2[(wk+m)*100 + 64 + wj] = a2[m];
                        }
                    }
                }
            }
            __syncthreads();
            // gi transpose (odd stride 33, conflict-light)
            #pragma unroll
            for (int q = 0; q < 6; ++q) {
                const int n = tx * 6 + q;
                lds[n*33 + ty*2]     = acc[0][q];
                lds[n*33 + ty*2 + 1] = acc[1][q];
            }
            __syncthreads();
            {   // GRU -> hb @4096
                const int jr = tid & 31, bq = (tid >> 5) * 4;
                const int j = j0 + jr;
                const float brr = b_ih[j] + b_hh[j];
                const float bzz = b_ih[1024 + j] + b_hh[1024 + j];
                const float bnn = b_ih[2048 + j];
                const float gnn = b_hh[2048 + j];
                #pragma unroll
                for (int i = 0; i < 4; ++i) {
                    const int b = bq + i;
                    const float rr = sig_(lds[jr*33 + b] + brr);
                    const float zz = sig_(lds[(32+jr)*33 + b] + bzz);
                    const float nn = tanhf(lds[(64+jr)*33 + b] + bnn + rr * gnn);
                    lds[4096 + jr*33 + b] = (1.f - zz) * nn;
                }
            }
            __syncthreads();
            {   // hT write, coalesced float4
                const int jj = tid >> 3, bq = (tid & 7) * 4;
                float4 v = { lds[4096 + jj*33 + bq],     lds[4096 + jj*33 + bq + 1],
                             lds[4096 + jj*33 + bq + 2], lds[4096 + jj*33 + bq + 3] };
                *(float4*)&hT[(size_t)(j0 + jj) * 512 + cb + bq] = v;
            }
            {   // out_h rows
                const int b = tid >> 3, q = tid & 7;
                if (cb + b < bsz) {
                    float4 v = { lds[4096 + (q*4+0)*33 + b], lds[4096 + (q*4+1)*33 + b],
                                 lds[4096 + (q*4+2)*33 + b], lds[4096 + (q*4+3)*33 + b] };
                    *(float4*)&out_h[(size_t)(ofs + cb + b) * 1024 + j0 + q*4] = v;
                }
            }
            __syncthreads();
        }
        cl_sync(cnt, go, nblk, t * 3 + 1, tid);

        // ===== phase B: ha = tanh(h @ Wa^T + ba); 64 units x 32 n-rows (BOTH families) =====
        for (int s = r; s < 64; s += nblk) {
            const int n0 = s * 32;
            const float* __restrict__ Wa = (n0 < 1024) ? W1a : W2a;
            const float* __restrict__ ba = (n0 < 1024) ? b1a : b2a;
            const int nr0 = n0 & 1023;
            const int tx = tid & 15, ty = tid >> 4;
            const int sk = tid >> 3, sb = (tid & 7) * 4;
            const int wn = tid >> 3, wk0 = (tid & 7) * 4;
            float acc[2][2] = {{0.f,0.f},{0.f,0.f}};

            float4 px, pw;
            px = *(const float4*)&hT[(size_t)sk * 512 + cb + sb];
            pw = *(const float4*)&Wa[(size_t)(nr0 + wn) * 1024 + wk0];
            {
                float* xs = lds; float* ws = lds + 2304;
                *(float4*)&xs[sk * 36 + sb] = px;
                const float* a0 = &pw.x;
                #pragma unroll
                for (int m = 0; m < 4; ++m) ws[(wk0+m)*36 + wn] = a0[m];
            }
            for (int kc = 0; kc < 32; ++kc) {
                __syncthreads();
                const int cur = kc & 1;
                if (kc < 31) {
                    const int kb = (kc + 1) * 32;
                    px = *(const float4*)&hT[(size_t)(kb + sk) * 512 + cb + sb];
                    pw = *(const float4*)&Wa[(size_t)(nr0 + wn) * 1024 + kb + wk0];
                }
                const float* xs = lds + cur * 1152;
                const float* ws = lds + 2304 + cur * 1152;
                #pragma unroll 8
                for (int kk = 0; kk < 32; ++kk) {
                    const float a0v = xs[kk*36 + ty*2];
                    const float a1v = xs[kk*36 + ty*2 + 1];
                    const float w0 = ws[kk*36 + tx*2];
                    const float w1 = ws[kk*36 + tx*2 + 1];
                    acc[0][0] = fmaf(a0v, w0, acc[0][0]);
                    acc[0][1] = fmaf(a0v, w1, acc[0][1]);
                    acc[1][0] = fmaf(a1v, w0, acc[1][0]);
                    acc[1][1] = fmaf(a1v, w1, acc[1][1]);
                }
                if (kc < 31) {
                    float* xs2 = lds + (cur ^ 1) * 1152;
                    float* ws2 = lds + 2304 + (cur ^ 1) * 1152;
                    *(float4*)&xs2[sk * 36 + sb] = px;
                    const float* a0 = &pw.x;
                    #pragma unroll
                    for (int m = 0; m < 4; ++m) ws2[(wk0+m)*36 + wn] = a0[m];
                }
            }
            __syncthreads();
            #pragma unroll
            for (int q = 0; q < 2; ++q) {
                const int n = tx * 2 + q;
                const float bias = ba[nr0 + n];
                lds[n*33 + ty*2]     = tanhf(acc[0][q] + bias);
                lds[n*33 + ty*2 + 1] = tanhf(acc[1][q] + bias);
            }
            __syncthreads();
            {   // haT write, coalesced float4
                const int nn = tid >> 3, bq = (tid & 7) * 4;
                float4 v = { lds[nn*33 + bq],     lds[nn*33 + bq + 1],
                             lds[nn*33 + bq + 2], lds[nn*33 + bq + 3] };
                *(float4*)&haT[(size_t)(n0 + nn) * 512 + cb + bq] = v;
            }
            __syncthreads();
        }
        cl_sync(cnt, go, nblk, t * 3 + 2, tid);

        // ===== phase C: p = ha @ Wb^T + bb (8 cols, both fams); scatter; x-fuse =====
        for (int s = r; s < 32; s += nblk) {
            const int c0 = s * 8;
            const int b = tid & 31, g = tid >> 5;         // g = k-eighth
            const int sk = tid >> 3, sb = (tid & 7) * 4;
            const int cw = (tid & 63) >> 3, ck = (tid & 7) * 4;
            float accf[2][8];
            #pragma unroll
            for (int f = 0; f < 2; ++f)
                #pragma unroll
                for (int c = 0; c < 8; ++c) accf[f][c] = 0.f;

            #pragma unroll 1
            for (int f = 0; f < 2; ++f) {
                const float* __restrict__ Wb = f ? W2b : W1b;
                const float* __restrict__ hap = haT + (size_t)f * 1024 * 512;
                float4 px, pw;
                px = *(const float4*)&hap[(size_t)sk * 512 + cb + sb];
                if (tid < 64) pw = *(const float4*)&Wb[(size_t)(c0 + cw) * 1024 + ck];
                {
                    float* xs = lds; float* ws = lds + 2304;
                    *(float4*)&xs[sk * 36 + sb] = px;
                    if (tid < 64) {
                        const float* a0 = &pw.x;
                        #pragma unroll
                        for (int m = 0; m < 4; ++m) ws[(ck+m)*12 + cw] = a0[m];
                    }
                }
                for (int kc = 0; kc < 32; ++kc) {
                    __syncthreads();
                    const int cur = kc & 1;
                    if (kc < 31) {
                        const int kb = (kc + 1) * 32;
                        px = *(const float4*)&hap[(size_t)(kb + sk) * 512 + cb + sb];
                        if (tid < 64) pw = *(const float4*)&Wb[(size_t)(c0 + cw) * 1024 + kb + ck];
                    }
                    const float* xs = lds + cur * 1152;
                    const float* ws = lds + 2304 + cur * 384;
                    #pragma unroll
                    for (int kq = 0; kq < 4; ++kq) {
                        const int kk = g * 4 + kq;
                        const float a = xs[kk*36 + b];
                        const float4 wlo = *(const float4*)&ws[kk*12];
                        const float4 whi = *(const float4*)&ws[kk*12 + 4];
                        accf[f][0] = fmaf(a, wlo.x, accf[f][0]);
                        accf[f][1] = fmaf(a, wlo.y, accf[f][1]);
                        accf[f][2] = fmaf(a, wlo.z, accf[f][2]);
                        accf[f][3] = fmaf(a, wlo.w, accf[f][3]);
                        accf[f][4] = fmaf(a, whi.x, accf[f][4]);
                        accf[f][5] = fmaf(a, whi.y, accf[f][5]);
                        accf[f][6] = fmaf(a, whi.z, accf[f][6]);
                        accf[f][7] = fmaf(a, whi.w, accf[f][7]);
                    }
                    if (kc < 31) {
                        float* xs2 = lds + (cur ^ 1) * 1152;
                        float* ws2 = lds + 2304 + (cur ^ 1) * 384;
                        *(float4*)&xs2[sk * 36 + sb] = px;
                        if (tid < 64) {
                            const float* a0 = &pw.x;
                            #pragma unroll
                            for (int m = 0; m < 4; ++m) ws2[(ck+m)*12 + cw] = a0[m];
                        }
                    }
                }
                // dump partials to red @3072 (own data, no sync needed before)
                #pragma unroll
                for (int c = 0; c < 8; ++c)
                    lds[3072 + ((f*8 + g)*8 + c)*33 + b] = accf[f][c];
                __syncthreads();          // staging buffers + red consistent for next f / epilogue
            }
            {   // epilogue: 8-way k reduce + bias; x-fuse; p bounce @7296
                const int cc = tid >> 5, bb = tid & 31;
                float p1 = b1b[c0 + cc], p2 = b2b[c0 + cc];
                #pragma unroll
                for (int g2 = 0; g2 < 8; ++g2) {
                    p1 += lds[3072 + ((0*8 + g2)*8 + cc)*33 + bb];
                    p2 += lds[3072 + ((1*8 + g2)*8 + cc)*33 + bb];
                }
                const float e = eps[(size_t)t * 131072 + (size_t)(cb + bb) * 256 + c0 + cc];
                xT[(size_t)(c0 + cc) * 512 + cb + bb] = fmaf(expf(0.5f * p2), e, p1);
                lds[7296 + bb*24 + cc]     = p1;
                lds[7296 + bb*24 + 8 + cc] = p2;
            }
            __syncthreads();
            {   // coalesced p scatter
                const int bb = tid >> 3, q = tid & 7;
                if (cb + bb < bsz) {
                    if (q < 2)
                        *(float4*)&out_p1[(size_t)(ofs + cb + bb) * 256 + c0 + q*4] =
                            *(const float4*)&lds[7296 + bb*24 + q*4];
                    else if (q < 4)
                        *(float4*)&out_p2[(size_t)(ofs + cb + bb) * 256 + c0 + (q-2)*4] =
                            *(const float4*)&lds[7296 + bb*24 + 8 + (q-2)*4];
                }
            }
            __syncthreads();
        }
        cl_sync(cnt, go, nblk, t * 3 + 3, tid);
    }
}

extern "C" void kernel_launch(void* const* d_in, const int* in_sizes, int n_in,
                              void* d_out, int out_size, void* d_ws, size_t ws_size,
                              hipStream_t stream)
{
    (void)in_sizes; (void)n_in; (void)ws_size;
    const int*   lengths = (const int*)  d_in[1];
    const float* eps     = (const float*)d_in[2];
    const float* W_ih    = (const float*)d_in[5];
    const float* b_ih    = (const float*)d_in[6];
    const float* b_hh    = (const float*)d_in[8];
    const float* W1a     = (const float*)d_in[9];
    const float* b1a     = (const float*)d_in[10];
    const float* W1b     = (const float*)d_in[11];
    const float* b1b     = (const float*)d_in[12];
    const float* W2a     = (const float*)d_in[13];
    const float* b2a     = (const float*)d_in[14];
    const float* W2b     = (const float*)d_in[15];
    const float* b2b     = (const float*)d_in[16];

    float* out = (float*)d_out;
    const size_t N = (size_t)out_size / 1536;
    float* out_p1 = out;
    float* out_p2 = out + N * 256;
    float* out_h  = out + N * 512;

    int*   bar = (int*)d_ws;                      // 4 KB barrier region
    float* xT  = (float*)((char*)d_ws + 4096);    // [256][512]
    float* hT  = xT + 131072;                     // [1024][512]
    float* haT = hT + 524288;                     // [2048][512]  (~6.8 MB total)

    hipMemsetAsync(d_ws, 0, 4096, stream);

    int dev = 0;
    (void)hipGetDevice(&dev);
    int ncu = 0;
    if (hipDeviceGetAttribute(&ncu, hipDeviceAttributeMultiprocessorCount, dev) != hipSuccess || ncu <= 0)
        ncu = 256;
    int maxB = 0;
    if (hipOccupancyMaxActiveBlocksPerMultiprocessor(&maxB, (const void*)kfused, 256, 0) != hipSuccess || maxB <= 0)
        maxB = 1;
    long cap = (long)maxB * (long)ncu;
    int grd = (cap < 512) ? (int)(cap & ~15L) : 512;
    if (grd < 16) grd = 16;

    for (;;) {
        int nblk = grd >> 4;
        void* args[] = {
            (void*)&lengths, (void*)&eps, (void*)&W_ih, (void*)&b_ih, (void*)&b_hh,
            (void*)&W1a, (void*)&b1a, (void*)&W1b, (void*)&b1b,
            (void*)&W2a, (void*)&b2a, (void*)&W2b, (void*)&b2b,
            (void*)&out_p1, (void*)&out_p2, (void*)&out_h,
            (void*)&bar, (void*)&xT, (void*)&hT, (void*)&haT, (void*)&nblk
        };
        hipError_t err = hipLaunchCooperativeKernel((void*)kfused, dim3(grd), dim3(256), args, 0, stream);
        if (err == hipSuccess || grd <= 16) break;
        grd = (grd >> 1) & ~15;
        if (grd < 16) grd = 16;
    }
}